// Round 11
// baseline (220.612 us; speedup 1.0000x reference)
//
#include <hip/hip_runtime.h>

#define HW_ 1024

typedef __attribute__((ext_vector_type(8))) short bf16x8;   // 8 bf16 = 4 VGPRs
typedef __attribute__((ext_vector_type(4))) short bf16x4;   // 8 B
typedef __attribute__((ext_vector_type(4))) float f32x4;

__device__ inline unsigned short f2bf(float f) {            // RNE f32->bf16
  unsigned int u = __float_as_uint(f);
  u += 0x7FFF + ((u >> 16) & 1);
  return (unsigned short)(u >> 16);
}
__device__ inline unsigned short f2bf_fast(float f) {       // ties-away (2 ops)
  return (unsigned short)((__float_as_uint(f) + 0x8000u) >> 16);
}
__device__ inline float bf2f(unsigned short h) {
  return __uint_as_float(((unsigned int)h) << 16);
}
__device__ inline void async_copy16(const void* g, void* l) {
  __builtin_amdgcn_global_load_lds(
      (const __attribute__((address_space(1))) unsigned int*)g,
      (__attribute__((address_space(3))) unsigned int*)l, 16, 0, 0);
}

// ---------------------------------------------------------------------------
// prep: [0,256) qprep transpose->hi/lo; [256,512) kvT f32 transpose;
// [512,1664) conv weights bf16. (wsplit removed: gemms read W f32 directly.)
// ---------------------------------------------------------------------------
__global__ __launch_bounds__(256) void prep(
    const float* __restrict__ Xq, const float* __restrict__ kv,
    const float* __restrict__ Woff1,
    short* __restrict__ Xh, short* __restrict__ Xl,
    short* __restrict__ wb, float* __restrict__ kvT)
{
  const int bid = blockIdx.x, t = threadIdx.x;
  if (bid < 256) {                      // qprep: (b,c,p) f32 -> (b,p,c) hi/lo
    int bpg = bid & 31, cg = bid >> 5;
    int bp = bpg * 256 + t;
    int b = bp >> 10, p = bp & 1023;
#pragma unroll
    for (int cc = 0; cc < 32; cc += 8) {
      int c0 = cg * 32 + cc;
      bf16x8 h8, l8;
#pragma unroll
      for (int j = 0; j < 8; ++j) {
        float f = Xq[((size_t)(b * 256 + c0 + j)) * HW_ + p];
        unsigned short h = f2bf(f);
        h8[j] = (short)h;
        l8[j] = (short)f2bf(f - bf2f(h));
      }
      *(bf16x8*)&Xh[(size_t)bp * 256 + c0] = h8;
      *(bf16x8*)&Xl[(size_t)bp * 256 + c0] = l8;
    }
  } else if (bid < 512) {               // kv transpose: (b,c,p) -> (b,p,c) f32
    int b2 = bid - 256;
    int bpg = b2 & 31, cg = b2 >> 5;
    int bp = bpg * 256 + t;
    int b = bp >> 10, p = bp & 1023;
#pragma unroll
    for (int cc = 0; cc < 32; cc += 8) {
      int c0 = cg * 32 + cc;
      float4 v0, v1;
      v0.x = kv[((size_t)(b * 256 + c0 + 0)) * HW_ + p];
      v0.y = kv[((size_t)(b * 256 + c0 + 1)) * HW_ + p];
      v0.z = kv[((size_t)(b * 256 + c0 + 2)) * HW_ + p];
      v0.w = kv[((size_t)(b * 256 + c0 + 3)) * HW_ + p];
      v1.x = kv[((size_t)(b * 256 + c0 + 4)) * HW_ + p];
      v1.y = kv[((size_t)(b * 256 + c0 + 5)) * HW_ + p];
      v1.z = kv[((size_t)(b * 256 + c0 + 6)) * HW_ + p];
      v1.w = kv[((size_t)(b * 256 + c0 + 7)) * HW_ + p];
      *(float4*)&kvT[(size_t)bp * 256 + c0]     = v0;
      *(float4*)&kvT[(size_t)bp * 256 + c0 + 4] = v1;
    }
  } else {                              // wprep conv weights
    int e = (bid - 512) * 256 + t;      // < 294912
    int c = e & 255;
    int o = (e >> 8) & 127;
    int tap = e >> 15;
    wb[e] = (short)f2bf(Woff1[((size_t)(o * 256 + c)) * 9 + tap]);
  }
}

// ---------------------------------------------------------------------------
// MFMA GEMM, M=256 K=256 N=8192, 3-pass split bf16 (~fp32). W read as f32
// and hi/lo-split in-register (kills wsplit; same bytes, same values).
// grid (256 nb, 2 mb), block 256 = 4 waves; wave = M 32 x N 32 -> 2 waves/SIMD.
// MODE 0: qt (bh,p,d)*log2e/sqrt32 + q hi/lo (b,p,c) via per-wave LDS
//   transpose -> 6 coalesced b128 stores (was 48 scattered).
// MODE 3: f32 (b,c,p) + bias (already coalesced).
// ---------------------------------------------------------------------------
template <int MODE>
__global__ __launch_bounds__(256) void gemm_mfma(
    const float* __restrict__ Wf,
    const short* __restrict__ Xh, const short* __restrict__ Xl,
    const float* __restrict__ bias, float* __restrict__ Yf,
    short* __restrict__ Yt, short* __restrict__ Yh2, short* __restrict__ Yl2)
{
  __shared__ short Th[4][32][40];   // per-wave hi tile [p][o pad40: 16B-aligned
  __shared__ short Tl[4][32][40];   //  rows, stride 20 dwords -> conflict-free]
  const int t    = threadIdx.x;
  const int w    = t >> 6;
  const int lane = t & 63;
  const int ln   = lane & 15;
  const int qd   = lane >> 4;
  const int bp0  = blockIdx.x * 32;
  const int om   = blockIdx.y * 128 + w * 32;

  f32x4 acc[2][2] = {};
#pragma unroll
  for (int k0 = 0; k0 < 256; k0 += 32) {
    bf16x8 Ah[2], Al[2], Bh[2], Bl[2];
#pragma unroll
    for (int mt = 0; mt < 2; ++mt) {
      const float* wp = &Wf[((size_t)(om + mt * 16 + ln)) * 256 + k0 + qd * 8];
      float4 f0 = *(const float4*)wp, f1 = *(const float4*)(wp + 4);
      float fv[8] = {f0.x, f0.y, f0.z, f0.w, f1.x, f1.y, f1.z, f1.w};
#pragma unroll
      for (int j = 0; j < 8; ++j) {
        unsigned short h = f2bf(fv[j]);
        Ah[mt][j] = (short)h;
        Al[mt][j] = (short)f2bf(fv[j] - bf2f(h));
      }
    }
#pragma unroll
    for (int nt = 0; nt < 2; ++nt) {
      size_t xi = ((size_t)(bp0 + nt * 16 + ln)) * 256 + k0 + qd * 8;
      Bh[nt] = *(const bf16x8*)&Xh[xi];
      Bl[nt] = *(const bf16x8*)&Xl[xi];
    }
#pragma unroll
    for (int mt = 0; mt < 2; ++mt)
#pragma unroll
      for (int nt = 0; nt < 2; ++nt) {
        acc[mt][nt] = __builtin_amdgcn_mfma_f32_16x16x32_bf16(Ah[mt], Bh[nt], acc[mt][nt], 0, 0, 0);
        acc[mt][nt] = __builtin_amdgcn_mfma_f32_16x16x32_bf16(Ah[mt], Bl[nt], acc[mt][nt], 0, 0, 0);
        acc[mt][nt] = __builtin_amdgcn_mfma_f32_16x16x32_bf16(Al[mt], Bh[nt], acc[mt][nt], 0, 0, 0);
      }
  }

  if (MODE == 3) {
#pragma unroll
    for (int mt = 0; mt < 2; ++mt)
#pragma unroll
      for (int i = 0; i < 4; ++i) {
        int o = om + mt * 16 + qd * 4 + i;
        float bo = bias[o];
#pragma unroll
        for (int nt = 0; nt < 2; ++nt) {
          int bp = bp0 + nt * 16 + ln;
          int b = bp >> 10, p = bp & 1023;
          Yf[((size_t)(b * 256 + o)) * HW_ + p] = acc[mt][nt][i] + bo;
        }
      }
  }
  if (MODE == 0) {
    // C -> per-wave LDS tiles (hi/lo), packed pair b32 writes
#pragma unroll
    for (int mt = 0; mt < 2; ++mt)
#pragma unroll
      for (int nt = 0; nt < 2; ++nt) {
        int pp = nt * 16 + ln;
#pragma unroll
        for (int i = 0; i < 4; i += 2) {
          int o = mt * 16 + qd * 4 + i;       // even -> 4B-aligned
          float fa = acc[mt][nt][i], fb = acc[mt][nt][i + 1];
          unsigned short ha = f2bf(fa), hb = f2bf(fb);
          unsigned short la = f2bf(fa - bf2f(ha)), lb = f2bf(fb - bf2f(hb));
          *(unsigned int*)&Th[w][pp][o] = (unsigned int)ha | ((unsigned int)hb << 16);
          *(unsigned int*)&Tl[w][pp][o] = (unsigned int)la | ((unsigned int)lb << 16);
        }
      }
    // read back coalesced (per-wave region; in-wave DS ordering suffices)
    const int b = bp0 >> 10, pl = bp0 & 1023, h = (om >> 5) & 7;
    const float sc = 0.25506063286f;   // (1/sqrt32)*log2(e)
#pragma unroll
    for (int k = 0; k < 2; ++k) {
      int idx = k * 64 + lane;           // 0..127
      int p = idx >> 2, oct = idx & 3;
      bf16x8 hi8 = *(const bf16x8*)&Th[w][p][oct * 8];
      bf16x8 lo8 = *(const bf16x8*)&Tl[w][p][oct * 8];
      bf16x8 q8;
#pragma unroll
      for (int j = 0; j < 8; ++j) {
        float f = bf2f((unsigned short)hi8[j]) + bf2f((unsigned short)lo8[j]);
        q8[j] = (short)f2bf(f * sc);
      }
      *(bf16x8*)&Yt[(((size_t)(b * 8 + h)) * 1024 + pl + p) * 32 + oct * 8] = q8;
      *(bf16x8*)&Yh2[((size_t)(bp0 + p)) * 256 + om + oct * 8] = hi8;
      *(bf16x8*)&Yl2[((size_t)(bp0 + p)) * 256 + om + oct * 8] = lo8;
    }
  }
}

// ---------------------------------------------------------------------------
// conv3x3 (split-bf16 MFMA) fused with offset head (unchanged).
// ---------------------------------------------------------------------------
__global__ __launch_bounds__(256) void conv3x3_off(
    const short* __restrict__ wb, const float* __restrict__ bias,
    const float* __restrict__ W2, const float* __restrict__ b2,
    const short* __restrict__ xh, const short* __restrict__ xl,
    float2* __restrict__ coords)
{
  __shared__ short Xs[2][3][34][32];
  __shared__ float red[4][32][2];
  const int t    = threadIdx.x;
  const int w    = t >> 6;
  const int lane = t & 63;
  const int ln   = lane & 15;
  const int qd   = lane >> 4;
  const int y0   = blockIdx.x;
  const int b    = blockIdx.y;
  const int o0   = w * 32;

  f32x4 acc[2][2] = {};

  for (int c0 = 0; c0 < 256; c0 += 32) {
    __syncthreads();
#pragma unroll
    for (int i = 0; i < 3; ++i) {
      int e   = t + 256 * i;
      int oct = e & 3;
      int x   = (e >> 2) & 31;
      int r   = (e >> 7) % 3;
      int hl  = e / 384;
      int yy  = y0 + r - 1;
      bf16x8 val = {};
      if (yy >= 0 && yy < 32) {
        const short* src = hl ? xl : xh;
        val = *(const bf16x8*)&src[((size_t)((b * 32 + yy) * 32 + x)) * 256 + c0 + oct * 8];
      }
      *(bf16x8*)&Xs[hl][r][x + 1][oct * 8] = val;
    }
    if (t < 48) {
      int oct = t & 3;
      int col = ((t >> 2) & 1) ? 33 : 0;
      int r   = (t >> 3) % 3;
      int hl  = t / 24;
      bf16x8 z = {};
      *(bf16x8*)&Xs[hl][r][col][oct * 8] = z;
    }
    __syncthreads();

#pragma unroll
    for (int tap = 0; tap < 9; ++tap) {
      const int ky = tap / 3, kx = tap % 3;
      bf16x8 afr[2];
#pragma unroll
      for (int m = 0; m < 2; ++m)
        afr[m] = *(const bf16x8*)&wb[((size_t)(tap * 128 + o0 + m * 16 + ln)) * 256
                                     + c0 + qd * 8];
#pragma unroll
      for (int nt = 0; nt < 2; ++nt) {
        int hc = nt * 16 + ln + kx;
        bf16x8 bh = *(const bf16x8*)&Xs[0][ky][hc][qd * 8];
        bf16x8 bl = *(const bf16x8*)&Xs[1][ky][hc][qd * 8];
#pragma unroll
        for (int m = 0; m < 2; ++m) {
          acc[m][nt] = __builtin_amdgcn_mfma_f32_16x16x32_bf16(afr[m], bh, acc[m][nt], 0, 0, 0);
          acc[m][nt] = __builtin_amdgcn_mfma_f32_16x16x32_bf16(afr[m], bl, acc[m][nt], 0, 0, 0);
        }
      }
    }
  }

  float ps0[2] = {0.f, 0.f}, ps1[2] = {0.f, 0.f};
#pragma unroll
  for (int m = 0; m < 2; ++m)
#pragma unroll
    for (int i = 0; i < 4; ++i) {
      int o = o0 + m * 16 + qd * 4 + i;
      float bo = bias[o];
      float w2a = W2[o], w2b = W2[128 + o];
#pragma unroll
      for (int nt = 0; nt < 2; ++nt) {
        float h = fmaxf(acc[m][nt][i] + bo, 0.f);
        ps0[nt] += w2a * h;
        ps1[nt] += w2b * h;
      }
    }
#pragma unroll
  for (int msk = 16; msk < 64; msk <<= 1) {
    ps0[0] += __shfl_xor(ps0[0], msk, 64);
    ps0[1] += __shfl_xor(ps0[1], msk, 64);
    ps1[0] += __shfl_xor(ps1[0], msk, 64);
    ps1[1] += __shfl_xor(ps1[1], msk, 64);
  }
  if (qd == 0) {
#pragma unroll
    for (int nt = 0; nt < 2; ++nt) {
      red[w][nt * 16 + ln][0] = ps0[nt];
      red[w][nt * 16 + ln][1] = ps1[nt];
    }
  }
  __syncthreads();
  if (t < 32) {
    int x = t;
    float s0 = red[0][x][0] + red[1][x][0] + red[2][x][0] + red[3][x][0] + b2[0];
    float s1 = red[0][x][1] + red[1][x][1] + red[2][x][1] + red[3][x][1] + b2[1];
    float gx = -1.f + 2.f * (float)x / 31.f;
    float gy = -1.f + 2.f * (float)y0 / 31.f;
    float vx = gx + 0.1f * s0;
    float vy = gy + 0.1f * s1;
    float px = fminf(fmaxf((vx + 1.f) * 0.5f * 31.f, 0.f), 31.f);
    float py = fminf(fmaxf((vy + 1.f) * 0.5f * 31.f, 0.f), 31.f);
    coords[b * 1024 + y0 * 32 + x] = make_float2(px, py);
  }
}

// ---------------------------------------------------------------------------
// K+V GEMM fused with bilinear sampling via kvT (b,p,c). W read as f32 with
// in-register hi/lo split. Epilogue writes tiled+swizzled kt/vt (unchanged).
// grid 256, block 256.
// ---------------------------------------------------------------------------
__global__ __launch_bounds__(256) void gemm_kv(
    const float* __restrict__ Wk, const float* __restrict__ Wv,
    const float* __restrict__ kvT, const float2* __restrict__ coords,
    short* __restrict__ kt, short* __restrict__ vt)
{
  __shared__ short XsH[32][264];
  __shared__ short XsL[32][264];
  const int t   = threadIdx.x;
  const int bp0 = blockIdx.x * 32;
  const int b   = bp0 >> 10;

#pragma unroll
  for (int it = 0; it < 4; ++it) {
    int e = t + 256 * it;            // 1024 tasks: 32 rows x 32 octs
    int oct = e & 31, row = e >> 5;
    float2 cd = coords[bp0 + row];
    float x0f = floorf(cd.x), y0f = floorf(cd.y);
    float wx = cd.x - x0f, wy = cd.y - y0f;
    int x0 = (int)x0f, y0 = (int)y0f;
    int x1 = min(x0 + 1, 31), y1 = min(y0 + 1, 31);
    float w00 = (1.f - wx) * (1.f - wy), w01 = wx * (1.f - wy);
    float w10 = (1.f - wx) * wy,         w11 = wx * wy;
    const float* r00 = &kvT[((size_t)(b * 1024 + y0 * 32 + x0)) * 256 + oct * 8];
    const float* r01 = &kvT[((size_t)(b * 1024 + y0 * 32 + x1)) * 256 + oct * 8];
    const float* r10 = &kvT[((size_t)(b * 1024 + y1 * 32 + x0)) * 256 + oct * 8];
    const float* r11 = &kvT[((size_t)(b * 1024 + y1 * 32 + x1)) * 256 + oct * 8];
    float4 a00 = *(const float4*)r00, b00 = *(const float4*)(r00 + 4);
    float4 a01 = *(const float4*)r01, b01 = *(const float4*)(r01 + 4);
    float4 a10 = *(const float4*)r10, b10 = *(const float4*)(r10 + 4);
    float4 a11 = *(const float4*)r11, b11 = *(const float4*)(r11 + 4);
    float v[8];
    v[0] = a00.x * w00 + a01.x * w01 + a10.x * w10 + a11.x * w11;
    v[1] = a00.y * w00 + a01.y * w01 + a10.y * w10 + a11.y * w11;
    v[2] = a00.z * w00 + a01.z * w01 + a10.z * w10 + a11.z * w11;
    v[3] = a00.w * w00 + a01.w * w01 + a10.w * w10 + a11.w * w11;
    v[4] = b00.x * w00 + b01.x * w01 + b10.x * w10 + b11.x * w11;
    v[5] = b00.y * w00 + b01.y * w01 + b10.y * w10 + b11.y * w11;
    v[6] = b00.z * w00 + b01.z * w01 + b10.z * w10 + b11.z * w11;
    v[7] = b00.w * w00 + b01.w * w01 + b10.w * w10 + b11.w * w11;
    bf16x8 h8, l8;
#pragma unroll
    for (int j = 0; j < 8; ++j) {
      unsigned short h = f2bf(v[j]);
      h8[j] = (short)h;
      l8[j] = (short)f2bf(v[j] - bf2f(h));
    }
    *(bf16x8*)&XsH[row][oct * 8] = h8;
    *(bf16x8*)&XsL[row][oct * 8] = l8;
  }
  __syncthreads();

  const int w    = t >> 6;
  const int lane = t & 63;
  const int ln   = lane & 15;
  const int qd   = lane >> 4;
  const float* WAf = (w < 2) ? Wk : Wv;
  const int om = (w & 1) * 128;

  f32x4 acc[8][2] = {};
#pragma unroll
  for (int k0 = 0; k0 < 256; k0 += 32) {
    bf16x8 Bh[2], Bl[2];
#pragma unroll
    for (int nt = 0; nt < 2; ++nt) {
      Bh[nt] = *(const bf16x8*)&XsH[nt * 16 + ln][k0 + qd * 8];
      Bl[nt] = *(const bf16x8*)&XsL[nt * 16 + ln][k0 + qd * 8];
    }
#pragma unroll
    for (int mt = 0; mt < 8; ++mt) {
      const float* wp = &WAf[((size_t)(om + mt * 16 + ln)) * 256 + k0 + qd * 8];
      float4 f0 = *(const float4*)wp, f1 = *(const float4*)(wp + 4);
      float fv[8] = {f0.x, f0.y, f0.z, f0.w, f1.x, f1.y, f1.z, f1.w};
      bf16x8 Ah, Al;
#pragma unroll
      for (int j = 0; j < 8; ++j) {
        unsigned short h = f2bf(fv[j]);
        Ah[j] = (short)h;
        Al[j] = (short)f2bf(fv[j] - bf2f(h));
      }
#pragma unroll
      for (int nt = 0; nt < 2; ++nt) {
        acc[mt][nt] = __builtin_amdgcn_mfma_f32_16x16x32_bf16(Ah, Bh[nt], acc[mt][nt], 0, 0, 0);
        acc[mt][nt] = __builtin_amdgcn_mfma_f32_16x16x32_bf16(Ah, Bl[nt], acc[mt][nt], 0, 0, 0);
        acc[mt][nt] = __builtin_amdgcn_mfma_f32_16x16x32_bf16(Al, Bh[nt], acc[mt][nt], 0, 0, 0);
      }
    }
  }

#pragma unroll
  for (int mt = 0; mt < 8; ++mt)
#pragma unroll
    for (int nt = 0; nt < 2; ++nt) {
      int p  = bp0 + nt * 16 + ln;
      int pl = p & 1023;
      int jt = pl >> 6, jl = pl & 63;
#pragma unroll
      for (int i = 0; i < 4; ++i) {
        int oc = om + mt * 16 + qd * 4 + i;      // channel within K or V
        unsigned short val = f2bf(acc[mt][nt][i]);
        int bhead = b * 8 + (oc >> 5), d = oc & 31;
        if (w < 2) {
          int cd2 = (d >> 3) ^ ((jl >> 2) & 3);
          kt[((((size_t)(bhead * 16 + jt)) * 64 + jl) * 4 + cd2) * 8 + (d & 7)] = (short)val;
        } else {
          int jjs = ((jl & 15) << 2) | (jl >> 4);       // sigma
          int cj = (jjs >> 3) ^ (d & 7);
          vt[((((size_t)(bhead * 16 + jt)) * 32 + d) * 8 + cj) * 8 + (jjs & 7)] = (short)val;
        }
      }
    }
}

// ---------------------------------------------------------------------------
// MFMA flash attention with async LDS double-buffered K/V (unchanged r10).
// grid (16, 64), block 256.
// ---------------------------------------------------------------------------
__global__ __launch_bounds__(256) void attn_mfma(
    const short* __restrict__ qt, const short* __restrict__ kt,
    const short* __restrict__ vt, short* __restrict__ aoh,
    short* __restrict__ aol)
{
  __shared__ __align__(16) short Ks[2][2048];
  __shared__ __align__(16) short Vs[2][2048];
  __shared__ __align__(16) short P[4][16][72];
  const int t    = threadIdx.x;
  const int w    = t >> 6;
  const int lane = t & 63;
  const int ln   = lane & 15;
  const int qd   = lane >> 4;
  const int bh   = blockIdx.y;
  const int q0   = blockIdx.x * 64 + w * 16;

  const short* ktb = kt + (size_t)bh * 32768;
  const short* vtb = vt + (size_t)bh * 32768;

  bf16x8 aq = *(const bf16x8*)&qt[((size_t)(bh * 1024 + q0 + ln)) * 32 + qd * 8];

  f32x4 acc[2] = {};
  float lacc[4] = {};
  const f32x4 zero = {0.f, 0.f, 0.f, 0.f};

  const int stoff = w * 512 + lane * 8;
  const int ldoff = w * 512;

  async_copy16(&ktb[stoff], &Ks[0][ldoff]);
  async_copy16(&vtb[stoff], &Vs[0][ldoff]);
  __syncthreads();

  for (int jt = 0; jt < 16; ++jt) {
    const int cur = jt & 1, nxt = cur ^ 1;
    if (jt < 15) {
      async_copy16(&ktb[(jt + 1) * 2048 + stoff], &Ks[nxt][ldoff]);
      async_copy16(&vtb[(jt + 1) * 2048 + stoff], &Vs[nxt][ldoff]);
    }

    bf16x8 bk[4], bv[2][2];
#pragma unroll
    for (int kk = 0; kk < 4; ++kk)
      bk[kk] = *(const bf16x8*)&Ks[cur][((kk * 16 + ln) * 4 + (qd ^ ((ln >> 2) & 3))) * 8];
#pragma unroll
    for (int kc = 0; kc < 2; ++kc)
#pragma unroll
      for (int ds = 0; ds < 2; ++ds)
        bv[kc][ds] = *(const bf16x8*)&Vs[cur][((ds * 16 + ln) * 8 + ((kc * 4 + qd) ^ (ln & 7))) * 8];

    f32x4 s[4];
#pragma unroll
    for (int kk = 0; kk < 4; ++kk)
      s[kk] = __builtin_amdgcn_mfma_f32_16x16x32_bf16(aq, bk[kk], zero, 0, 0, 0);

#pragma unroll
    for (int i = 0; i < 4; ++i) {
      float p0 = __builtin_amdgcn_exp2f(s[0][i]);
      float p1 = __builtin_amdgcn_exp2f(s[1][i]);
      float p2 = __builtin_amdgcn_exp2f(s[2][i]);
      float p3 = __builtin_amdgcn_exp2f(s[3][i]);
      s[0][i] = p0; s[1][i] = p1; s[2][i] = p2; s[3][i] = p3;
      lacc[i] += (p0 + p1) + (p2 + p3);
    }
#pragma unroll
    for (int i = 0; i < 4; ++i) {
      bf16x4 p4;
#pragma unroll
      for (int kk = 0; kk < 4; ++kk) p4[kk] = (short)f2bf_fast(s[kk][i]);
      *(bf16x4*)&P[w][qd * 4 + i][4 * ln] = p4;
    }
#pragma unroll
    for (int kc = 0; kc < 2; ++kc) {
      bf16x8 ap = *(const bf16x8*)&P[w][ln][kc * 32 + qd * 8];
#pragma unroll
      for (int ds = 0; ds < 2; ++ds)
        acc[ds] = __builtin_amdgcn_mfma_f32_16x16x32_bf16(ap, bv[kc][ds], acc[ds], 0, 0, 0);
    }

    __syncthreads();
  }

  const int b = bh >> 3, h = bh & 7;
#pragma unroll
  for (int i = 0; i < 4; ++i) {
    float l = lacc[i];
    l += __shfl_xor(l, 1, 64);
    l += __shfl_xor(l, 2, 64);
    l += __shfl_xor(l, 4, 64);
    l += __shfl_xor(l, 8, 64);
    float inv = 1.f / l;
    int qrow = q0 + qd * 4 + i;
#pragma unroll
    for (int ds = 0; ds < 2; ++ds) {
      float v = acc[ds][i] * inv;
      unsigned short hh = f2bf(v);
      size_t idx = ((size_t)(b * 1024 + qrow)) * 256 + h * 32 + ds * 16 + ln;
      aoh[idx] = (short)hh;
      aol[idx] = (short)f2bf(v - bf2f(hh));
    }
  }
}

// ---------------------------------------------------------------------------
extern "C" void kernel_launch(void* const* d_in, const int* in_sizes, int n_in,
                              void* d_out, int out_size, void* d_ws, size_t ws_size,
                              hipStream_t stream)
{
  const float* query_map = (const float*)d_in[0];
  const float* kv_map    = (const float*)d_in[1];
  const float* Wq        = (const float*)d_in[2];
  const float* Wk        = (const float*)d_in[3];
  const float* Wv        = (const float*)d_in[4];
  const float* Woff1     = (const float*)d_in[5];
  const float* boff1     = (const float*)d_in[6];
  const float* Woff2     = (const float*)d_in[7];
  const float* boff2     = (const float*)d_in[8];
  const float* Wout      = (const float*)d_in[9];
  const float* bout      = (const float*)d_in[10];
  float* out = (float*)d_out;
  char* base = (char*)d_ws;

  const size_t MB = 1u << 20;
  float* coords = (float*)(base);              // 64 KB
  short* qt     = (short*)(base + 1 * MB);     // 4 MB (bh,p,d) pre-scaled
  short* kt     = (short*)(base + 5 * MB);     // 4 MB tiled+swizzled
  short* vt     = (short*)(base + 9 * MB);     // 4 MB tiled+swizzled
  short* bufAh  = (short*)(base + 13 * MB);    // 4 MB query_map hi (b,p,c)
  short* bufAl  = (short*)(base + 17 * MB);    // 4 MB query_map lo
  short* bufBh  = (short*)(base + 21 * MB);    // 4 MB q hi -> ao hi
  short* bufBl  = (short*)(base + 25 * MB);    // 4 MB q lo -> ao lo
  short* wb     = (short*)(base + 29 * MB);    // 576 KB conv weights bf16
  float* kvT    = (float*)(base + 30 * MB);    // 8 MB kv_map (b,p,c) f32

  dim3 blk(256);
  prep<<<dim3(1664), blk, 0, stream>>>(query_map, kv_map, Woff1,
                                       bufAh, bufAl, wb, kvT);
  gemm_mfma<0><<<dim3(256, 2), blk, 0, stream>>>(Wq, bufAh, bufAl,
                                                 nullptr, nullptr, qt, bufBh, bufBl);
  conv3x3_off<<<dim3(32, 8), blk, 0, stream>>>(wb, boff1, Woff2, boff2,
                                               bufBh, bufBl, (float2*)coords);
  gemm_kv<<<dim3(256), blk, 0, stream>>>(Wk, Wv, kvT, (const float2*)coords, kt, vt);
  attn_mfma<<<dim3(16, 64), blk, 0, stream>>>(qt, kt, vt, bufBh, bufBl);
  gemm_mfma<3><<<dim3(256, 2), blk, 0, stream>>>(Wout, bufBh, bufBl,
                                                 bout, out, nullptr, nullptr, nullptr);
}

// Round 12
// 205.788 us; speedup vs baseline: 1.0720x; 1.0720x over previous
//
#include <hip/hip_runtime.h>

#define HW_ 1024

typedef __attribute__((ext_vector_type(8))) short bf16x8;   // 8 bf16 = 4 VGPRs
typedef __attribute__((ext_vector_type(4))) short bf16x4;   // 8 B
typedef __attribute__((ext_vector_type(4))) float f32x4;

__device__ inline unsigned short f2bf(float f) {            // RNE f32->bf16
  unsigned int u = __float_as_uint(f);
  u += 0x7FFF + ((u >> 16) & 1);
  return (unsigned short)(u >> 16);
}
__device__ inline unsigned short f2bf_fast(float f) {       // ties-away (2 ops)
  return (unsigned short)((__float_as_uint(f) + 0x8000u) >> 16);
}
__device__ inline float bf2f(unsigned short h) {
  return __uint_as_float(((unsigned int)h) << 16);
}
__device__ inline void async_copy16(const void* g, void* l) {
  __builtin_amdgcn_global_load_lds(
      (const __attribute__((address_space(1))) unsigned int*)g,
      (__attribute__((address_space(3))) unsigned int*)l, 16, 0, 0);
}

// ---------------------------------------------------------------------------
// prep (r10 version): [0,256) qprep; [256,512) kvT; [512,1536) wsplit;
// [1536,2688) conv weights.
// ---------------------------------------------------------------------------
__global__ __launch_bounds__(256) void prep(
    const float* __restrict__ Xq, const float* __restrict__ kv,
    const float* __restrict__ W0, const float* __restrict__ W1,
    const float* __restrict__ W2, const float* __restrict__ W3,
    const float* __restrict__ Woff1,
    short* __restrict__ Xh, short* __restrict__ Xl,
    short* __restrict__ WH, short* __restrict__ WL, short* __restrict__ wb,
    float* __restrict__ kvT)
{
  const int bid = blockIdx.x, t = threadIdx.x;
  if (bid < 256) {                      // qprep: (b,c,p) f32 -> (b,p,c) hi/lo
    int bpg = bid & 31, cg = bid >> 5;
    int bp = bpg * 256 + t;
    int b = bp >> 10, p = bp & 1023;
#pragma unroll
    for (int cc = 0; cc < 32; cc += 8) {
      int c0 = cg * 32 + cc;
      bf16x8 h8, l8;
#pragma unroll
      for (int j = 0; j < 8; ++j) {
        float f = Xq[((size_t)(b * 256 + c0 + j)) * HW_ + p];
        unsigned short h = f2bf(f);
        h8[j] = (short)h;
        l8[j] = (short)f2bf(f - bf2f(h));
      }
      *(bf16x8*)&Xh[(size_t)bp * 256 + c0] = h8;
      *(bf16x8*)&Xl[(size_t)bp * 256 + c0] = l8;
    }
  } else if (bid < 512) {               // kv transpose: (b,c,p) -> (b,p,c) f32
    int b2 = bid - 256;
    int bpg = b2 & 31, cg = b2 >> 5;
    int bp = bpg * 256 + t;
    int b = bp >> 10, p = bp & 1023;
#pragma unroll
    for (int cc = 0; cc < 32; cc += 8) {
      int c0 = cg * 32 + cc;
      float4 v0, v1;
      v0.x = kv[((size_t)(b * 256 + c0 + 0)) * HW_ + p];
      v0.y = kv[((size_t)(b * 256 + c0 + 1)) * HW_ + p];
      v0.z = kv[((size_t)(b * 256 + c0 + 2)) * HW_ + p];
      v0.w = kv[((size_t)(b * 256 + c0 + 3)) * HW_ + p];
      v1.x = kv[((size_t)(b * 256 + c0 + 4)) * HW_ + p];
      v1.y = kv[((size_t)(b * 256 + c0 + 5)) * HW_ + p];
      v1.z = kv[((size_t)(b * 256 + c0 + 6)) * HW_ + p];
      v1.w = kv[((size_t)(b * 256 + c0 + 7)) * HW_ + p];
      *(float4*)&kvT[(size_t)bp * 256 + c0]     = v0;
      *(float4*)&kvT[(size_t)bp * 256 + c0 + 4] = v1;
    }
  } else if (bid < 1536) {              // wsplit
    int b2 = bid - 512;
    int mat = b2 >> 8;
    int idx = (b2 & 255) * 256 + t;
    const float* W = (mat == 0) ? W0 : (mat == 1) ? W1 : (mat == 2) ? W2 : W3;
    float f = W[idx];
    unsigned short h = f2bf(f);
    WH[mat * 65536 + idx] = (short)h;
    WL[mat * 65536 + idx] = (short)f2bf(f - bf2f(h));
  } else {                              // wprep conv weights
    int e = (bid - 1536) * 256 + t;     // < 294912
    int c = e & 255;
    int o = (e >> 8) & 127;
    int tap = e >> 15;
    wb[e] = (short)f2bf(Woff1[((size_t)(o * 256 + c)) * 9 + tap]);
  }
}

// ---------------------------------------------------------------------------
// LDS-free MFMA GEMM (r10 version), M=256 K=256 N=8192, 3-pass split bf16.
// ---------------------------------------------------------------------------
template <int MODE>
__global__ __launch_bounds__(256) void gemm_mfma(
    const short* __restrict__ Wh, const short* __restrict__ Wl,
    const short* __restrict__ Xh, const short* __restrict__ Xl,
    const float* __restrict__ bias, float* __restrict__ Yf,
    short* __restrict__ Yt, short* __restrict__ Yh2, short* __restrict__ Yl2)
{
  const int t    = threadIdx.x;
  const int w    = t >> 6;
  const int lane = t & 63;
  const int ln   = lane & 15;
  const int qd   = lane >> 4;
  const int bp0  = blockIdx.x * 32;
  const int om   = w * 64;

  f32x4 acc[4][2] = {};
#pragma unroll
  for (int k0 = 0; k0 < 256; k0 += 32) {
    bf16x8 Ah[4], Al[4], Bh[2], Bl[2];
#pragma unroll
    for (int mt = 0; mt < 4; ++mt) {
      size_t wi = ((size_t)(om + mt * 16 + ln)) * 256 + k0 + qd * 8;
      Ah[mt] = *(const bf16x8*)&Wh[wi];
      Al[mt] = *(const bf16x8*)&Wl[wi];
    }
#pragma unroll
    for (int nt = 0; nt < 2; ++nt) {
      size_t xi = ((size_t)(bp0 + nt * 16 + ln)) * 256 + k0 + qd * 8;
      Bh[nt] = *(const bf16x8*)&Xh[xi];
      Bl[nt] = *(const bf16x8*)&Xl[xi];
    }
#pragma unroll
    for (int mt = 0; mt < 4; ++mt)
#pragma unroll
      for (int nt = 0; nt < 2; ++nt) {
        acc[mt][nt] = __builtin_amdgcn_mfma_f32_16x16x32_bf16(Ah[mt], Bh[nt], acc[mt][nt], 0, 0, 0);
        acc[mt][nt] = __builtin_amdgcn_mfma_f32_16x16x32_bf16(Ah[mt], Bl[nt], acc[mt][nt], 0, 0, 0);
        acc[mt][nt] = __builtin_amdgcn_mfma_f32_16x16x32_bf16(Al[mt], Bh[nt], acc[mt][nt], 0, 0, 0);
      }
  }

  if (MODE == 3) {
#pragma unroll
    for (int mt = 0; mt < 4; ++mt)
#pragma unroll
      for (int i = 0; i < 4; ++i) {
        int o = om + mt * 16 + qd * 4 + i;
        float bo = bias[o];
#pragma unroll
        for (int nt = 0; nt < 2; ++nt) {
          int bp = bp0 + nt * 16 + ln;
          int b = bp >> 10, p = bp & 1023;
          Yf[((size_t)(b * 256 + o)) * HW_ + p] = acc[mt][nt][i] + bo;
        }
      }
  }
  if (MODE == 0) {
    const float sc = 0.25506063286f;   // (1/sqrt32)*log2(e)
#pragma unroll
    for (int mt = 0; mt < 4; ++mt)
#pragma unroll
      for (int nt = 0; nt < 2; ++nt) {
        int bp = bp0 + nt * 16 + ln;
        int b = bp >> 10, p = bp & 1023;
#pragma unroll
        for (int i = 0; i < 4; ++i) {
          int o = om + mt * 16 + qd * 4 + i;
          int h = o >> 5, d = o & 31;
          Yt[(((size_t)(b * 8 + h)) * 1024 + p) * 32 + d] = (short)f2bf(acc[mt][nt][i] * sc);
        }
        int ob = om + mt * 16 + qd * 4;
        bf16x4 h4, l4;
#pragma unroll
        for (int i = 0; i < 4; ++i) {
          float f = acc[mt][nt][i];
          unsigned short h = f2bf(f);
          h4[i] = (short)h;
          l4[i] = (short)f2bf(f - bf2f(h));
        }
        *(bf16x4*)&Yh2[(size_t)bp * 256 + ob] = h4;
        *(bf16x4*)&Yl2[(size_t)bp * 256 + ob] = l4;
      }
  }
}

// ---------------------------------------------------------------------------
// conv3x3 (split-bf16 MFMA) fused with offset head (unchanged).
// ---------------------------------------------------------------------------
__global__ __launch_bounds__(256) void conv3x3_off(
    const short* __restrict__ wb, const float* __restrict__ bias,
    const float* __restrict__ W2, const float* __restrict__ b2,
    const short* __restrict__ xh, const short* __restrict__ xl,
    float2* __restrict__ coords)
{
  __shared__ short Xs[2][3][34][32];
  __shared__ float red[4][32][2];
  const int t    = threadIdx.x;
  const int w    = t >> 6;
  const int lane = t & 63;
  const int ln   = lane & 15;
  const int qd   = lane >> 4;
  const int y0   = blockIdx.x;
  const int b    = blockIdx.y;
  const int o0   = w * 32;

  f32x4 acc[2][2] = {};

  for (int c0 = 0; c0 < 256; c0 += 32) {
    __syncthreads();
#pragma unroll
    for (int i = 0; i < 3; ++i) {
      int e   = t + 256 * i;
      int oct = e & 3;
      int x   = (e >> 2) & 31;
      int r   = (e >> 7) % 3;
      int hl  = e / 384;
      int yy  = y0 + r - 1;
      bf16x8 val = {};
      if (yy >= 0 && yy < 32) {
        const short* src = hl ? xl : xh;
        val = *(const bf16x8*)&src[((size_t)((b * 32 + yy) * 32 + x)) * 256 + c0 + oct * 8];
      }
      *(bf16x8*)&Xs[hl][r][x + 1][oct * 8] = val;
    }
    if (t < 48) {
      int oct = t & 3;
      int col = ((t >> 2) & 1) ? 33 : 0;
      int r   = (t >> 3) % 3;
      int hl  = t / 24;
      bf16x8 z = {};
      *(bf16x8*)&Xs[hl][r][col][oct * 8] = z;
    }
    __syncthreads();

#pragma unroll
    for (int tap = 0; tap < 9; ++tap) {
      const int ky = tap / 3, kx = tap % 3;
      bf16x8 afr[2];
#pragma unroll
      for (int m = 0; m < 2; ++m)
        afr[m] = *(const bf16x8*)&wb[((size_t)(tap * 128 + o0 + m * 16 + ln)) * 256
                                     + c0 + qd * 8];
#pragma unroll
      for (int nt = 0; nt < 2; ++nt) {
        int hc = nt * 16 + ln + kx;
        bf16x8 bh = *(const bf16x8*)&Xs[0][ky][hc][qd * 8];
        bf16x8 bl = *(const bf16x8*)&Xs[1][ky][hc][qd * 8];
#pragma unroll
        for (int m = 0; m < 2; ++m) {
          acc[m][nt] = __builtin_amdgcn_mfma_f32_16x16x32_bf16(afr[m], bh, acc[m][nt], 0, 0, 0);
          acc[m][nt] = __builtin_amdgcn_mfma_f32_16x16x32_bf16(afr[m], bl, acc[m][nt], 0, 0, 0);
        }
      }
    }
  }

  float ps0[2] = {0.f, 0.f}, ps1[2] = {0.f, 0.f};
#pragma unroll
  for (int m = 0; m < 2; ++m)
#pragma unroll
    for (int i = 0; i < 4; ++i) {
      int o = o0 + m * 16 + qd * 4 + i;
      float bo = bias[o];
      float w2a = W2[o], w2b = W2[128 + o];
#pragma unroll
      for (int nt = 0; nt < 2; ++nt) {
        float h = fmaxf(acc[m][nt][i] + bo, 0.f);
        ps0[nt] += w2a * h;
        ps1[nt] += w2b * h;
      }
    }
#pragma unroll
  for (int msk = 16; msk < 64; msk <<= 1) {
    ps0[0] += __shfl_xor(ps0[0], msk, 64);
    ps0[1] += __shfl_xor(ps0[1], msk, 64);
    ps1[0] += __shfl_xor(ps1[0], msk, 64);
    ps1[1] += __shfl_xor(ps1[1], msk, 64);
  }
  if (qd == 0) {
#pragma unroll
    for (int nt = 0; nt < 2; ++nt) {
      red[w][nt * 16 + ln][0] = ps0[nt];
      red[w][nt * 16 + ln][1] = ps1[nt];
    }
  }
  __syncthreads();
  if (t < 32) {
    int x = t;
    float s0 = red[0][x][0] + red[1][x][0] + red[2][x][0] + red[3][x][0] + b2[0];
    float s1 = red[0][x][1] + red[1][x][1] + red[2][x][1] + red[3][x][1] + b2[1];
    float gx = -1.f + 2.f * (float)x / 31.f;
    float gy = -1.f + 2.f * (float)y0 / 31.f;
    float vx = gx + 0.1f * s0;
    float vy = gy + 0.1f * s1;
    float px = fminf(fmaxf((vx + 1.f) * 0.5f * 31.f, 0.f), 31.f);
    float py = fminf(fmaxf((vy + 1.f) * 0.5f * 31.f, 0.f), 31.f);
    coords[b * 1024 + y0 * 32 + x] = make_float2(px, py);
  }
}

// ---------------------------------------------------------------------------
// K+V GEMM fused with bilinear sampling via kvT. PARALLELIZED: grid (256, 2)
// — blockIdx.y picks K (Wk) or V (Wv); per-wave M halves (4 mt), 512 blocks
// = 2 blocks/CU for latency hiding. A-fragments from precomputed bf16 WH/WL
// (single b128 load — the r11 f32 in-register split is reverted: it
// lengthened the un-hideable serial chain). Epilogue unchanged (tiled+swizzle).
// ---------------------------------------------------------------------------
__global__ __launch_bounds__(256) void gemm_kv(
    const short* __restrict__ WH, const short* __restrict__ WL,
    const float* __restrict__ kvT, const float2* __restrict__ coords,
    short* __restrict__ kt, short* __restrict__ vt)
{
  __shared__ short XsH[32][264];
  __shared__ short XsL[32][264];
  const int t   = threadIdx.x;
  const int bp0 = blockIdx.x * 32;
  const int b   = bp0 >> 10;
  const int mat = blockIdx.y;          // 0 = K, 1 = V

#pragma unroll
  for (int it = 0; it < 4; ++it) {
    int e = t + 256 * it;            // 1024 tasks: 32 rows x 32 octs
    int oct = e & 31, row = e >> 5;
    float2 cd = coords[bp0 + row];
    float x0f = floorf(cd.x), y0f = floorf(cd.y);
    float wx = cd.x - x0f, wy = cd.y - y0f;
    int x0 = (int)x0f, y0 = (int)y0f;
    int x1 = min(x0 + 1, 31), y1 = min(y0 + 1, 31);
    float w00 = (1.f - wx) * (1.f - wy), w01 = wx * (1.f - wy);
    float w10 = (1.f - wx) * wy,         w11 = wx * wy;
    const float* r00 = &kvT[((size_t)(b * 1024 + y0 * 32 + x0)) * 256 + oct * 8];
    const float* r01 = &kvT[((size_t)(b * 1024 + y0 * 32 + x1)) * 256 + oct * 8];
    const float* r10 = &kvT[((size_t)(b * 1024 + y1 * 32 + x0)) * 256 + oct * 8];
    const float* r11 = &kvT[((size_t)(b * 1024 + y1 * 32 + x1)) * 256 + oct * 8];
    float4 a00 = *(const float4*)r00, b00 = *(const float4*)(r00 + 4);
    float4 a01 = *(const float4*)r01, b01 = *(const float4*)(r01 + 4);
    float4 a10 = *(const float4*)r10, b10 = *(const float4*)(r10 + 4);
    float4 a11 = *(const float4*)r11, b11 = *(const float4*)(r11 + 4);
    float v[8];
    v[0] = a00.x * w00 + a01.x * w01 + a10.x * w10 + a11.x * w11;
    v[1] = a00.y * w00 + a01.y * w01 + a10.y * w10 + a11.y * w11;
    v[2] = a00.z * w00 + a01.z * w01 + a10.z * w10 + a11.z * w11;
    v[3] = a00.w * w00 + a01.w * w01 + a10.w * w10 + a11.w * w11;
    v[4] = b00.x * w00 + b01.x * w01 + b10.x * w10 + b11.x * w11;
    v[5] = b00.y * w00 + b01.y * w01 + b10.y * w10 + b11.y * w11;
    v[6] = b00.z * w00 + b01.z * w01 + b10.z * w10 + b11.z * w11;
    v[7] = b00.w * w00 + b01.w * w01 + b10.w * w10 + b11.w * w11;
    bf16x8 h8, l8;
#pragma unroll
    for (int j = 0; j < 8; ++j) {
      unsigned short h = f2bf(v[j]);
      h8[j] = (short)h;
      l8[j] = (short)f2bf(v[j] - bf2f(h));
    }
    *(bf16x8*)&XsH[row][oct * 8] = h8;
    *(bf16x8*)&XsL[row][oct * 8] = l8;
  }
  __syncthreads();

  const int w    = t >> 6;
  const int lane = t & 63;
  const int ln   = lane & 15;
  const int qd   = lane >> 4;
  const short* WAh = WH + (mat ? 131072 : 65536);   // Wv : Wk (bf16 hi)
  const short* WAl = WL + (mat ? 131072 : 65536);
  const int om = w * 64;               // wave covers 64 of the 256 rows

  f32x4 acc[4][2] = {};
#pragma unroll
  for (int k0 = 0; k0 < 256; k0 += 32) {
    bf16x8 Bh[2], Bl[2];
#pragma unroll
    for (int nt = 0; nt < 2; ++nt) {
      Bh[nt] = *(const bf16x8*)&XsH[nt * 16 + ln][k0 + qd * 8];
      Bl[nt] = *(const bf16x8*)&XsL[nt * 16 + ln][k0 + qd * 8];
    }
#pragma unroll
    for (int mt = 0; mt < 4; ++mt) {
      size_t wi = ((size_t)(om + mt * 16 + ln)) * 256 + k0 + qd * 8;
      bf16x8 Ah = *(const bf16x8*)&WAh[wi];
      bf16x8 Al = *(const bf16x8*)&WAl[wi];
#pragma unroll
      for (int nt = 0; nt < 2; ++nt) {
        acc[mt][nt] = __builtin_amdgcn_mfma_f32_16x16x32_bf16(Ah, Bh[nt], acc[mt][nt], 0, 0, 0);
        acc[mt][nt] = __builtin_amdgcn_mfma_f32_16x16x32_bf16(Ah, Bl[nt], acc[mt][nt], 0, 0, 0);
        acc[mt][nt] = __builtin_amdgcn_mfma_f32_16x16x32_bf16(Al, Bh[nt], acc[mt][nt], 0, 0, 0);
      }
    }
  }

#pragma unroll
  for (int mt = 0; mt < 4; ++mt)
#pragma unroll
    for (int nt = 0; nt < 2; ++nt) {
      int p  = bp0 + nt * 16 + ln;
      int pl = p & 1023;
      int jt = pl >> 6, jl = pl & 63;
#pragma unroll
      for (int i = 0; i < 4; ++i) {
        int oc = om + mt * 16 + qd * 4 + i;      // channel within K or V
        unsigned short val = f2bf(acc[mt][nt][i]);
        int bhead = b * 8 + (oc >> 5), d = oc & 31;
        if (mat == 0) {
          int cd2 = (d >> 3) ^ ((jl >> 2) & 3);
          kt[((((size_t)(bhead * 16 + jt)) * 64 + jl) * 4 + cd2) * 8 + (d & 7)] = (short)val;
        } else {
          int jjs = ((jl & 15) << 2) | (jl >> 4);       // sigma
          int cj = (jjs >> 3) ^ (d & 7);
          vt[((((size_t)(bhead * 16 + jt)) * 32 + d) * 8 + cj) * 8 + (jjs & 7)] = (short)val;
        }
      }
    }
}

// ---------------------------------------------------------------------------
// MFMA flash attention with async LDS double-buffered K/V (unchanged r10).
// grid (16, 64), block 256.
// ---------------------------------------------------------------------------
__global__ __launch_bounds__(256) void attn_mfma(
    const short* __restrict__ qt, const short* __restrict__ kt,
    const short* __restrict__ vt, short* __restrict__ aoh,
    short* __restrict__ aol)
{
  __shared__ __align__(16) short Ks[2][2048];
  __shared__ __align__(16) short Vs[2][2048];
  __shared__ __align__(16) short P[4][16][72];
  const int t    = threadIdx.x;
  const int w    = t >> 6;
  const int lane = t & 63;
  const int ln   = lane & 15;
  const int qd   = lane >> 4;
  const int bh   = blockIdx.y;
  const int q0   = blockIdx.x * 64 + w * 16;

  const short* ktb = kt + (size_t)bh * 32768;
  const short* vtb = vt + (size_t)bh * 32768;

  bf16x8 aq = *(const bf16x8*)&qt[((size_t)(bh * 1024 + q0 + ln)) * 32 + qd * 8];

  f32x4 acc[2] = {};
  float lacc[4] = {};
  const f32x4 zero = {0.f, 0.f, 0.f, 0.f};

  const int stoff = w * 512 + lane * 8;
  const int ldoff = w * 512;

  async_copy16(&ktb[stoff], &Ks[0][ldoff]);
  async_copy16(&vtb[stoff], &Vs[0][ldoff]);
  __syncthreads();

  for (int jt = 0; jt < 16; ++jt) {
    const int cur = jt & 1, nxt = cur ^ 1;
    if (jt < 15) {
      async_copy16(&ktb[(jt + 1) * 2048 + stoff], &Ks[nxt][ldoff]);
      async_copy16(&vtb[(jt + 1) * 2048 + stoff], &Vs[nxt][ldoff]);
    }

    bf16x8 bk[4], bv[2][2];
#pragma unroll
    for (int kk = 0; kk < 4; ++kk)
      bk[kk] = *(const bf16x8*)&Ks[cur][((kk * 16 + ln) * 4 + (qd ^ ((ln >> 2) & 3))) * 8];
#pragma unroll
    for (int kc = 0; kc < 2; ++kc)
#pragma unroll
      for (int ds = 0; ds < 2; ++ds)
        bv[kc][ds] = *(const bf16x8*)&Vs[cur][((ds * 16 + ln) * 8 + ((kc * 4 + qd) ^ (ln & 7))) * 8];

    f32x4 s[4];
#pragma unroll
    for (int kk = 0; kk < 4; ++kk)
      s[kk] = __builtin_amdgcn_mfma_f32_16x16x32_bf16(aq, bk[kk], zero, 0, 0, 0);

#pragma unroll
    for (int i = 0; i < 4; ++i) {
      float p0 = __builtin_amdgcn_exp2f(s[0][i]);
      float p1 = __builtin_amdgcn_exp2f(s[1][i]);
      float p2 = __builtin_amdgcn_exp2f(s[2][i]);
      float p3 = __builtin_amdgcn_exp2f(s[3][i]);
      s[0][i] = p0; s[1][i] = p1; s[2][i] = p2; s[3][i] = p3;
      lacc[i] += (p0 + p1) + (p2 + p3);
    }
#pragma unroll
    for (int i = 0; i < 4; ++i) {
      bf16x4 p4;
#pragma unroll
      for (int kk = 0; kk < 4; ++kk) p4[kk] = (short)f2bf_fast(s[kk][i]);
      *(bf16x4*)&P[w][qd * 4 + i][4 * ln] = p4;
    }
#pragma unroll
    for (int kc = 0; kc < 2; ++kc) {
      bf16x8 ap = *(const bf16x8*)&P[w][ln][kc * 32 + qd * 8];
#pragma unroll
      for (int ds = 0; ds < 2; ++ds)
        acc[ds] = __builtin_amdgcn_mfma_f32_16x16x32_bf16(ap, bv[kc][ds], acc[ds], 0, 0, 0);
    }

    __syncthreads();
  }

  const int b = bh >> 3, h = bh & 7;
#pragma unroll
  for (int i = 0; i < 4; ++i) {
    float l = lacc[i];
    l += __shfl_xor(l, 1, 64);
    l += __shfl_xor(l, 2, 64);
    l += __shfl_xor(l, 4, 64);
    l += __shfl_xor(l, 8, 64);
    float inv = 1.f / l;
    int qrow = q0 + qd * 4 + i;
#pragma unroll
    for (int ds = 0; ds < 2; ++ds) {
      float v = acc[ds][i] * inv;
      unsigned short hh = f2bf(v);
      size_t idx = ((size_t)(b * 1024 + qrow)) * 256 + h * 32 + ds * 16 + ln;
      aoh[idx] = (short)hh;
      aol[idx] = (short)f2bf(v - bf2f(hh));
    }
  }
}

// ---------------------------------------------------------------------------
extern "C" void kernel_launch(void* const* d_in, const int* in_sizes, int n_in,
                              void* d_out, int out_size, void* d_ws, size_t ws_size,
                              hipStream_t stream)
{
  const float* query_map = (const float*)d_in[0];
  const float* kv_map    = (const float*)d_in[1];
  const float* Wq        = (const float*)d_in[2];
  const float* Wk        = (const float*)d_in[3];
  const float* Wv        = (const float*)d_in[4];
  const float* Woff1     = (const float*)d_in[5];
  const float* boff1     = (const float*)d_in[6];
  const float* Woff2     = (const float*)d_in[7];
  const float* boff2     = (const float*)d_in[8];
  const float* Wout      = (const float*)d_in[9];
  const float* bout      = (const float*)d_in[10];
  float* out = (float*)d_out;
  char* base = (char*)d_ws;

  const size_t MB = 1u << 20;
  float* coords = (float*)(base);              // 64 KB
  short* qt     = (short*)(base + 1 * MB);     // 4 MB (bh,p,d) pre-scaled
  short* kt     = (short*)(base + 5 * MB);     // 4 MB tiled+swizzled
  short* vt     = (short*)(base + 9 * MB);     // 4 MB tiled+swizzled
  short* bufAh  = (short*)(base + 13 * MB);    // 4 MB query_map hi (b,p,c)
  short* bufAl  = (short*)(base + 17 * MB);    // 4 MB query_map lo
  short* bufBh  = (short*)(base + 21 * MB);    // 4 MB q hi -> ao hi
  short* bufBl  = (short*)(base + 25 * MB);    // 4 MB q lo -> ao lo
  short* wb     = (short*)(base + 29 * MB);    // 576 KB conv weights bf16
  short* WH     = (short*)(base + 30 * MB);    // 512 KB Wq/Wk/Wv/Wout hi
  short* WL     = (short*)(base + 31 * MB);    // 512 KB lo
  float* kvT    = (float*)(base + 32 * MB);    // 8 MB kv_map (b,p,c) f32

  dim3 blk(256);
  prep<<<dim3(2688), blk, 0, stream>>>(query_map, kv_map, Wq, Wk, Wv, Wout,
                                       Woff1, bufAh, bufAl, WH, WL, wb, kvT);
  gemm_mfma<0><<<dim3(256), blk, 0, stream>>>(WH, WL, bufAh, bufAl,
                                              nullptr, nullptr, qt, bufBh, bufBl);
  conv3x3_off<<<dim3(32, 8), blk, 0, stream>>>(wb, boff1, Woff2, boff2,
                                               bufBh, bufBl, (float2*)coords);
  gemm_kv<<<dim3(256, 2), blk, 0, stream>>>(WH, WL, kvT, (const float2*)coords, kt, vt);
  attn_mfma<<<dim3(16, 64), blk, 0, stream>>>(qt, kt, vt, bufBh, bufBl);
  gemm_mfma<3><<<dim3(256), blk, 0, stream>>>(WH + 196608, WL + 196608, bufBh, bufBl,
                                              bout, out, nullptr, nullptr, nullptr);
}

// Round 13
// 198.920 us; speedup vs baseline: 1.1091x; 1.0345x over previous
//
#include <hip/hip_runtime.h>

#define HW_ 1024

typedef __attribute__((ext_vector_type(8))) short bf16x8;   // 8 bf16 = 4 VGPRs
typedef __attribute__((ext_vector_type(4))) short bf16x4;   // 8 B
typedef __attribute__((ext_vector_type(4))) float f32x4;

__device__ inline unsigned short f2bf(float f) {            // RNE f32->bf16
  unsigned int u = __float_as_uint(f);
  u += 0x7FFF + ((u >> 16) & 1);
  return (unsigned short)(u >> 16);
}
__device__ inline unsigned short f2bf_fast(float f) {       // ties-away (2 ops)
  return (unsigned short)((__float_as_uint(f) + 0x8000u) >> 16);
}
__device__ inline float bf2f(unsigned short h) {
  return __uint_as_float(((unsigned int)h) << 16);
}
__device__ inline void async_copy16(const void* g, void* l) {
  __builtin_amdgcn_global_load_lds(
      (const __attribute__((address_space(1))) unsigned int*)g,
      (__attribute__((address_space(3))) unsigned int*)l, 16, 0, 0);
}

// ---------------------------------------------------------------------------
// prep: [0,256) kvT transpose via LDS tile (coalesced loads AND stores);
// [256,1280) wsplit Wq/Wk/Wv/Wout; [1280,2432) conv weights.
// qprep is GONE — gemm_mfma<0> stages/splits query_map itself.
// ---------------------------------------------------------------------------
__global__ __launch_bounds__(256) void prep(
    const float* __restrict__ kv,
    const float* __restrict__ W0, const float* __restrict__ W1,
    const float* __restrict__ W2, const float* __restrict__ W3,
    const float* __restrict__ Woff1,
    short* __restrict__ WH, short* __restrict__ WL, short* __restrict__ wb,
    float* __restrict__ kvT)
{
  __shared__ float T[256][33];          // [c][p] pad33 -> conflict-free writes
  const int bid = blockIdx.x, t = threadIdx.x;
  if (bid < 256) {                      // kvT: (b,c,p) -> (b,p,c) f32
    int b = bid >> 5, p0 = (bid & 31) * 32;
    int pp = t & 31, cg = t >> 5;       // cg 0..7
#pragma unroll
    for (int i = 0; i < 32; ++i) {      // 32 independent coalesced loads
      int c = cg * 32 + i;
      T[c][pp] = kv[((size_t)(b * 256 + c)) * HW_ + p0 + pp];
    }
    __syncthreads();
#pragma unroll
    for (int r = 0; r < 8; ++r) {       // coalesced float4 stores
      int e = t + 256 * r;
      int c4 = (e & 63) * 4, pp2 = e >> 6;
      float4 v4;
      v4.x = T[c4 + 0][pp2];
      v4.y = T[c4 + 1][pp2];
      v4.z = T[c4 + 2][pp2];
      v4.w = T[c4 + 3][pp2];
      *(float4*)&kvT[((size_t)(b * 1024 + p0 + pp2)) * 256 + c4] = v4;
    }
  } else if (bid < 1280) {              // wsplit
    int b2 = bid - 256;
    int mat = b2 >> 8;
    int idx = (b2 & 255) * 256 + t;
    const float* W = (mat == 0) ? W0 : (mat == 1) ? W1 : (mat == 2) ? W2 : W3;
    float f = W[idx];
    unsigned short h = f2bf(f);
    WH[mat * 65536 + idx] = (short)h;
    WL[mat * 65536 + idx] = (short)f2bf(f - bf2f(h));
  } else {                              // wprep conv weights
    int e = (bid - 1280) * 256 + t;     // < 294912
    int c = e & 255;
    int o = (e >> 8) & 127;
    int tap = e >> 15;
    wb[e] = (short)f2bf(Woff1[((size_t)(o * 256 + c)) * 9 + tap]);
  }
}

// ---------------------------------------------------------------------------
// MFMA GEMM, M=256 K=256 N=8192, 3-pass split bf16 (~fp32).
// MODE 0: X = query_map f32 (b,c,p), staged+split per k-step through LDS
//   (coalesced 128B row loads; stride-40 rows -> 2-way banks = free).
//   Outputs qt (bh,p,d)*log2e/sqrt32 + q hi/lo (b,p,c).
// MODE 3: X = (b,p,c) hi/lo bf16, LDS-free (r10 path). f32 out + bias.
// grid 256, block 256 = 4 waves (M 64 each).
// ---------------------------------------------------------------------------
template <int MODE>
__global__ __launch_bounds__(256) void gemm_mfma(
    const short* __restrict__ Wh, const short* __restrict__ Wl,
    const float* __restrict__ Xf,
    const short* __restrict__ Xh, const short* __restrict__ Xl,
    const float* __restrict__ bias, float* __restrict__ Yf,
    short* __restrict__ Yt, short* __restrict__ Yh2, short* __restrict__ Yl2)
{
  __shared__ short Bsh[32][40];   // [p][c] pad 40 (80B rows: 16B-aligned)
  __shared__ short Bsl[32][40];
  const int t    = threadIdx.x;
  const int w    = t >> 6;
  const int lane = t & 63;
  const int ln   = lane & 15;
  const int qd   = lane >> 4;
  const int bp0  = blockIdx.x * 32;
  const int om   = w * 64;
  const int bB   = bp0 >> 10, p0l = bp0 & 1023;

  f32x4 acc[4][2] = {};
#pragma unroll
  for (int k0 = 0; k0 < 256; k0 += 32) {
    bf16x8 Ah[4], Al[4], Bh[2], Bl[2];
    if (MODE == 0) {                    // stage + split X tile
      __syncthreads();
      int pp = t & 31, cg = t >> 5;     // cg 0..7, 4 c's each
      float fv[4];
#pragma unroll
      for (int j = 0; j < 4; ++j)
        fv[j] = Xf[((size_t)(bB * 256 + k0 + cg * 4 + j)) * HW_ + p0l + pp];
      bf16x4 h4, l4;
#pragma unroll
      for (int j = 0; j < 4; ++j) {
        unsigned short h = f2bf(fv[j]);
        h4[j] = (short)h;
        l4[j] = (short)f2bf(fv[j] - bf2f(h));
      }
      *(bf16x4*)&Bsh[pp][cg * 4] = h4;
      *(bf16x4*)&Bsl[pp][cg * 4] = l4;
      __syncthreads();
    }
#pragma unroll
    for (int mt = 0; mt < 4; ++mt) {
      size_t wi = ((size_t)(om + mt * 16 + ln)) * 256 + k0 + qd * 8;
      Ah[mt] = *(const bf16x8*)&Wh[wi];
      Al[mt] = *(const bf16x8*)&Wl[wi];
    }
    if (MODE == 0) {
#pragma unroll
      for (int nt = 0; nt < 2; ++nt) {
        Bh[nt] = *(const bf16x8*)&Bsh[nt * 16 + ln][qd * 8];
        Bl[nt] = *(const bf16x8*)&Bsl[nt * 16 + ln][qd * 8];
      }
    } else {
#pragma unroll
      for (int nt = 0; nt < 2; ++nt) {
        size_t xi = ((size_t)(bp0 + nt * 16 + ln)) * 256 + k0 + qd * 8;
        Bh[nt] = *(const bf16x8*)&Xh[xi];
        Bl[nt] = *(const bf16x8*)&Xl[xi];
      }
    }
#pragma unroll
    for (int mt = 0; mt < 4; ++mt)
#pragma unroll
      for (int nt = 0; nt < 2; ++nt) {
        acc[mt][nt] = __builtin_amdgcn_mfma_f32_16x16x32_bf16(Ah[mt], Bh[nt], acc[mt][nt], 0, 0, 0);
        acc[mt][nt] = __builtin_amdgcn_mfma_f32_16x16x32_bf16(Ah[mt], Bl[nt], acc[mt][nt], 0, 0, 0);
        acc[mt][nt] = __builtin_amdgcn_mfma_f32_16x16x32_bf16(Al[mt], Bh[nt], acc[mt][nt], 0, 0, 0);
      }
  }

  if (MODE == 3) {
#pragma unroll
    for (int mt = 0; mt < 4; ++mt)
#pragma unroll
      for (int i = 0; i < 4; ++i) {
        int o = om + mt * 16 + qd * 4 + i;
        float bo = bias[o];
#pragma unroll
        for (int nt = 0; nt < 2; ++nt) {
          int bp = bp0 + nt * 16 + ln;
          int b = bp >> 10, p = bp & 1023;
          Yf[((size_t)(b * 256 + o)) * HW_ + p] = acc[mt][nt][i] + bo;
        }
      }
  }
  if (MODE == 0) {
    const float sc = 0.25506063286f;   // (1/sqrt32)*log2(e)
#pragma unroll
    for (int mt = 0; mt < 4; ++mt)
#pragma unroll
      for (int nt = 0; nt < 2; ++nt) {
        int bp = bp0 + nt * 16 + ln;
        int b = bp >> 10, p = bp & 1023;
#pragma unroll
        for (int i = 0; i < 4; ++i) {
          int o = om + mt * 16 + qd * 4 + i;
          int h = o >> 5, d = o & 31;
          Yt[(((size_t)(b * 8 + h)) * 1024 + p) * 32 + d] = (short)f2bf(acc[mt][nt][i] * sc);
        }
        int ob = om + mt * 16 + qd * 4;
        bf16x4 h4, l4;
#pragma unroll
        for (int i = 0; i < 4; ++i) {
          float f = acc[mt][nt][i];
          unsigned short h = f2bf(f);
          h4[i] = (short)h;
          l4[i] = (short)f2bf(f - bf2f(h));
        }
        *(bf16x4*)&Yh2[(size_t)bp * 256 + ob] = h4;
        *(bf16x4*)&Yl2[(size_t)bp * 256 + ob] = l4;
      }
  }
}

// ---------------------------------------------------------------------------
// conv3x3 (split-bf16 MFMA) fused with offset head (unchanged).
// ---------------------------------------------------------------------------
__global__ __launch_bounds__(256) void conv3x3_off(
    const short* __restrict__ wb, const float* __restrict__ bias,
    const float* __restrict__ W2, const float* __restrict__ b2,
    const short* __restrict__ xh, const short* __restrict__ xl,
    float2* __restrict__ coords)
{
  __shared__ short Xs[2][3][34][32];
  __shared__ float red[4][32][2];
  const int t    = threadIdx.x;
  const int w    = t >> 6;
  const int lane = t & 63;
  const int ln   = lane & 15;
  const int qd   = lane >> 4;
  const int y0   = blockIdx.x;
  const int b    = blockIdx.y;
  const int o0   = w * 32;

  f32x4 acc[2][2] = {};

  for (int c0 = 0; c0 < 256; c0 += 32) {
    __syncthreads();
#pragma unroll
    for (int i = 0; i < 3; ++i) {
      int e   = t + 256 * i;
      int oct = e & 3;
      int x   = (e >> 2) & 31;
      int r   = (e >> 7) % 3;
      int hl  = e / 384;
      int yy  = y0 + r - 1;
      bf16x8 val = {};
      if (yy >= 0 && yy < 32) {
        const short* src = hl ? xl : xh;
        val = *(const bf16x8*)&src[((size_t)((b * 32 + yy) * 32 + x)) * 256 + c0 + oct * 8];
      }
      *(bf16x8*)&Xs[hl][r][x + 1][oct * 8] = val;
    }
    if (t < 48) {
      int oct = t & 3;
      int col = ((t >> 2) & 1) ? 33 : 0;
      int r   = (t >> 3) % 3;
      int hl  = t / 24;
      bf16x8 z = {};
      *(bf16x8*)&Xs[hl][r][col][oct * 8] = z;
    }
    __syncthreads();

#pragma unroll
    for (int tap = 0; tap < 9; ++tap) {
      const int ky = tap / 3, kx = tap % 3;
      bf16x8 afr[2];
#pragma unroll
      for (int m = 0; m < 2; ++m)
        afr[m] = *(const bf16x8*)&wb[((size_t)(tap * 128 + o0 + m * 16 + ln)) * 256
                                     + c0 + qd * 8];
#pragma unroll
      for (int nt = 0; nt < 2; ++nt) {
        int hc = nt * 16 + ln + kx;
        bf16x8 bh = *(const bf16x8*)&Xs[0][ky][hc][qd * 8];
        bf16x8 bl = *(const bf16x8*)&Xs[1][ky][hc][qd * 8];
#pragma unroll
        for (int m = 0; m < 2; ++m) {
          acc[m][nt] = __builtin_amdgcn_mfma_f32_16x16x32_bf16(afr[m], bh, acc[m][nt], 0, 0, 0);
          acc[m][nt] = __builtin_amdgcn_mfma_f32_16x16x32_bf16(afr[m], bl, acc[m][nt], 0, 0, 0);
        }
      }
    }
  }

  float ps0[2] = {0.f, 0.f}, ps1[2] = {0.f, 0.f};
#pragma unroll
  for (int m = 0; m < 2; ++m)
#pragma unroll
    for (int i = 0; i < 4; ++i) {
      int o = o0 + m * 16 + qd * 4 + i;
      float bo = bias[o];
      float w2a = W2[o], w2b = W2[128 + o];
#pragma unroll
      for (int nt = 0; nt < 2; ++nt) {
        float h = fmaxf(acc[m][nt][i] + bo, 0.f);
        ps0[nt] += w2a * h;
        ps1[nt] += w2b * h;
      }
    }
#pragma unroll
  for (int msk = 16; msk < 64; msk <<= 1) {
    ps0[0] += __shfl_xor(ps0[0], msk, 64);
    ps0[1] += __shfl_xor(ps0[1], msk, 64);
    ps1[0] += __shfl_xor(ps1[0], msk, 64);
    ps1[1] += __shfl_xor(ps1[1], msk, 64);
  }
  if (qd == 0) {
#pragma unroll
    for (int nt = 0; nt < 2; ++nt) {
      red[w][nt * 16 + ln][0] = ps0[nt];
      red[w][nt * 16 + ln][1] = ps1[nt];
    }
  }
  __syncthreads();
  if (t < 32) {
    int x = t;
    float s0 = red[0][x][0] + red[1][x][0] + red[2][x][0] + red[3][x][0] + b2[0];
    float s1 = red[0][x][1] + red[1][x][1] + red[2][x][1] + red[3][x][1] + b2[1];
    float gx = -1.f + 2.f * (float)x / 31.f;
    float gy = -1.f + 2.f * (float)y0 / 31.f;
    float vx = gx + 0.1f * s0;
    float vy = gy + 0.1f * s1;
    float px = fminf(fmaxf((vx + 1.f) * 0.5f * 31.f, 0.f), 31.f);
    float py = fminf(fmaxf((vy + 1.f) * 0.5f * 31.f, 0.f), 31.f);
    coords[b * 1024 + y0 * 32 + x] = make_float2(px, py);
  }
}

// ---------------------------------------------------------------------------
// K+V GEMM fused with bilinear sampling via kvT, grid (256,2) (r12 version).
// ---------------------------------------------------------------------------
__global__ __launch_bounds__(256) void gemm_kv(
    const short* __restrict__ WH, const short* __restrict__ WL,
    const float* __restrict__ kvT, const float2* __restrict__ coords,
    short* __restrict__ kt, short* __restrict__ vt)
{
  __shared__ short XsH[32][264];
  __shared__ short XsL[32][264];
  const int t   = threadIdx.x;
  const int bp0 = blockIdx.x * 32;
  const int b   = bp0 >> 10;
  const int mat = blockIdx.y;          // 0 = K, 1 = V

#pragma unroll
  for (int it = 0; it < 4; ++it) {
    int e = t + 256 * it;            // 1024 tasks: 32 rows x 32 octs
    int oct = e & 31, row = e >> 5;
    float2 cd = coords[bp0 + row];
    float x0f = floorf(cd.x), y0f = floorf(cd.y);
    float wx = cd.x - x0f, wy = cd.y - y0f;
    int x0 = (int)x0f, y0 = (int)y0f;
    int x1 = min(x0 + 1, 31), y1 = min(y0 + 1, 31);
    float w00 = (1.f - wx) * (1.f - wy), w01 = wx * (1.f - wy);
    float w10 = (1.f - wx) * wy,         w11 = wx * wy;
    const float* r00 = &kvT[((size_t)(b * 1024 + y0 * 32 + x0)) * 256 + oct * 8];
    const float* r01 = &kvT[((size_t)(b * 1024 + y0 * 32 + x1)) * 256 + oct * 8];
    const float* r10 = &kvT[((size_t)(b * 1024 + y1 * 32 + x0)) * 256 + oct * 8];
    const float* r11 = &kvT[((size_t)(b * 1024 + y1 * 32 + x1)) * 256 + oct * 8];
    float4 a00 = *(const float4*)r00, b00 = *(const float4*)(r00 + 4);
    float4 a01 = *(const float4*)r01, b01 = *(const float4*)(r01 + 4);
    float4 a10 = *(const float4*)r10, b10 = *(const float4*)(r10 + 4);
    float4 a11 = *(const float4*)r11, b11 = *(const float4*)(r11 + 4);
    float v[8];
    v[0] = a00.x * w00 + a01.x * w01 + a10.x * w10 + a11.x * w11;
    v[1] = a00.y * w00 + a01.y * w01 + a10.y * w10 + a11.y * w11;
    v[2] = a00.z * w00 + a01.z * w01 + a10.z * w10 + a11.z * w11;
    v[3] = a00.w * w00 + a01.w * w01 + a10.w * w10 + a11.w * w11;
    v[4] = b00.x * w00 + b01.x * w01 + b10.x * w10 + b11.x * w11;
    v[5] = b00.y * w00 + b01.y * w01 + b10.y * w10 + b11.y * w11;
    v[6] = b00.z * w00 + b01.z * w01 + b10.z * w10 + b11.z * w11;
    v[7] = b00.w * w00 + b01.w * w01 + b10.w * w10 + b11.w * w11;
    bf16x8 h8, l8;
#pragma unroll
    for (int j = 0; j < 8; ++j) {
      unsigned short h = f2bf(v[j]);
      h8[j] = (short)h;
      l8[j] = (short)f2bf(v[j] - bf2f(h));
    }
    *(bf16x8*)&XsH[row][oct * 8] = h8;
    *(bf16x8*)&XsL[row][oct * 8] = l8;
  }
  __syncthreads();

  const int w    = t >> 6;
  const int lane = t & 63;
  const int ln   = lane & 15;
  const int qd   = lane >> 4;
  const short* WAh = WH + (mat ? 131072 : 65536);   // Wv : Wk (bf16 hi)
  const short* WAl = WL + (mat ? 131072 : 65536);
  const int om = w * 64;               // wave covers 64 of the 256 rows

  f32x4 acc[4][2] = {};
#pragma unroll
  for (int k0 = 0; k0 < 256; k0 += 32) {
    bf16x8 Bh[2], Bl[2];
#pragma unroll
    for (int nt = 0; nt < 2; ++nt) {
      Bh[nt] = *(const bf16x8*)&XsH[nt * 16 + ln][k0 + qd * 8];
      Bl[nt] = *(const bf16x8*)&XsL[nt * 16 + ln][k0 + qd * 8];
    }
#pragma unroll
    for (int mt = 0; mt < 4; ++mt) {
      size_t wi = ((size_t)(om + mt * 16 + ln)) * 256 + k0 + qd * 8;
      bf16x8 Ah = *(const bf16x8*)&WAh[wi];
      bf16x8 Al = *(const bf16x8*)&WAl[wi];
#pragma unroll
      for (int nt = 0; nt < 2; ++nt) {
        acc[mt][nt] = __builtin_amdgcn_mfma_f32_16x16x32_bf16(Ah, Bh[nt], acc[mt][nt], 0, 0, 0);
        acc[mt][nt] = __builtin_amdgcn_mfma_f32_16x16x32_bf16(Ah, Bl[nt], acc[mt][nt], 0, 0, 0);
        acc[mt][nt] = __builtin_amdgcn_mfma_f32_16x16x32_bf16(Al, Bh[nt], acc[mt][nt], 0, 0, 0);
      }
    }
  }

#pragma unroll
  for (int mt = 0; mt < 4; ++mt)
#pragma unroll
    for (int nt = 0; nt < 2; ++nt) {
      int p  = bp0 + nt * 16 + ln;
      int pl = p & 1023;
      int jt = pl >> 6, jl = pl & 63;
#pragma unroll
      for (int i = 0; i < 4; ++i) {
        int oc = om + mt * 16 + qd * 4 + i;      // channel within K or V
        unsigned short val = f2bf(acc[mt][nt][i]);
        int bhead = b * 8 + (oc >> 5), d = oc & 31;
        if (mat == 0) {
          int cd2 = (d >> 3) ^ ((jl >> 2) & 3);
          kt[((((size_t)(bhead * 16 + jt)) * 64 + jl) * 4 + cd2) * 8 + (d & 7)] = (short)val;
        } else {
          int jjs = ((jl & 15) << 2) | (jl >> 4);       // sigma
          int cj = (jjs >> 3) ^ (d & 7);
          vt[((((size_t)(bhead * 16 + jt)) * 32 + d) * 8 + cj) * 8 + (jjs & 7)] = (short)val;
        }
      }
    }
}

// ---------------------------------------------------------------------------
// MFMA flash attention with async LDS double-buffered K/V (unchanged r10).
// grid (16, 64), block 256.
// ---------------------------------------------------------------------------
__global__ __launch_bounds__(256) void attn_mfma(
    const short* __restrict__ qt, const short* __restrict__ kt,
    const short* __restrict__ vt, short* __restrict__ aoh,
    short* __restrict__ aol)
{
  __shared__ __align__(16) short Ks[2][2048];
  __shared__ __align__(16) short Vs[2][2048];
  __shared__ __align__(16) short P[4][16][72];
  const int t    = threadIdx.x;
  const int w    = t >> 6;
  const int lane = t & 63;
  const int ln   = lane & 15;
  const int qd   = lane >> 4;
  const int bh   = blockIdx.y;
  const int q0   = blockIdx.x * 64 + w * 16;

  const short* ktb = kt + (size_t)bh * 32768;
  const short* vtb = vt + (size_t)bh * 32768;

  bf16x8 aq = *(const bf16x8*)&qt[((size_t)(bh * 1024 + q0 + ln)) * 32 + qd * 8];

  f32x4 acc[2] = {};
  float lacc[4] = {};
  const f32x4 zero = {0.f, 0.f, 0.f, 0.f};

  const int stoff = w * 512 + lane * 8;
  const int ldoff = w * 512;

  async_copy16(&ktb[stoff], &Ks[0][ldoff]);
  async_copy16(&vtb[stoff], &Vs[0][ldoff]);
  __syncthreads();

  for (int jt = 0; jt < 16; ++jt) {
    const int cur = jt & 1, nxt = cur ^ 1;
    if (jt < 15) {
      async_copy16(&ktb[(jt + 1) * 2048 + stoff], &Ks[nxt][ldoff]);
      async_copy16(&vtb[(jt + 1) * 2048 + stoff], &Vs[nxt][ldoff]);
    }

    bf16x8 bk[4], bv[2][2];
#pragma unroll
    for (int kk = 0; kk < 4; ++kk)
      bk[kk] = *(const bf16x8*)&Ks[cur][((kk * 16 + ln) * 4 + (qd ^ ((ln >> 2) & 3))) * 8];
#pragma unroll
    for (int kc = 0; kc < 2; ++kc)
#pragma unroll
      for (int ds = 0; ds < 2; ++ds)
        bv[kc][ds] = *(const bf16x8*)&Vs[cur][((ds * 16 + ln) * 8 + ((kc * 4 + qd) ^ (ln & 7))) * 8];

    f32x4 s[4];
#pragma unroll
    for (int kk = 0; kk < 4; ++kk)
      s[kk] = __builtin_amdgcn_mfma_f32_16x16x32_bf16(aq, bk[kk], zero, 0, 0, 0);

#pragma unroll
    for (int i = 0; i < 4; ++i) {
      float p0 = __builtin_amdgcn_exp2f(s[0][i]);
      float p1 = __builtin_amdgcn_exp2f(s[1][i]);
      float p2 = __builtin_amdgcn_exp2f(s[2][i]);
      float p3 = __builtin_amdgcn_exp2f(s[3][i]);
      s[0][i] = p0; s[1][i] = p1; s[2][i] = p2; s[3][i] = p3;
      lacc[i] += (p0 + p1) + (p2 + p3);
    }
#pragma unroll
    for (int i = 0; i < 4; ++i) {
      bf16x4 p4;
#pragma unroll
      for (int kk = 0; kk < 4; ++kk) p4[kk] = (short)f2bf_fast(s[kk][i]);
      *(bf16x4*)&P[w][qd * 4 + i][4 * ln] = p4;
    }
#pragma unroll
    for (int kc = 0; kc < 2; ++kc) {
      bf16x8 ap = *(const bf16x8*)&P[w][ln][kc * 32 + qd * 8];
#pragma unroll
      for (int ds = 0; ds < 2; ++ds)
        acc[ds] = __builtin_amdgcn_mfma_f32_16x16x32_bf16(ap, bv[kc][ds], acc[ds], 0, 0, 0);
    }

    __syncthreads();
  }

  const int b = bh >> 3, h = bh & 7;
#pragma unroll
  for (int i = 0; i < 4; ++i) {
    float l = lacc[i];
    l += __shfl_xor(l, 1, 64);
    l += __shfl_xor(l, 2, 64);
    l += __shfl_xor(l, 4, 64);
    l += __shfl_xor(l, 8, 64);
    float inv = 1.f / l;
    int qrow = q0 + qd * 4 + i;
#pragma unroll
    for (int ds = 0; ds < 2; ++ds) {
      float v = acc[ds][i] * inv;
      unsigned short hh = f2bf(v);
      size_t idx = ((size_t)(b * 1024 + qrow)) * 256 + h * 32 + ds * 16 + ln;
      aoh[idx] = (short)hh;
      aol[idx] = (short)f2bf(v - bf2f(hh));
    }
  }
}

// ---------------------------------------------------------------------------
extern "C" void kernel_launch(void* const* d_in, const int* in_sizes, int n_in,
                              void* d_out, int out_size, void* d_ws, size_t ws_size,
                              hipStream_t stream)
{
  const float* query_map = (const float*)d_in[0];
  const float* kv_map    = (const float*)d_in[1];
  const float* Wq        = (const float*)d_in[2];
  const float* Wk        = (const float*)d_in[3];
  const float* Wv        = (const float*)d_in[4];
  const float* Woff1     = (const float*)d_in[5];
  const float* boff1     = (const float*)d_in[6];
  const float* Woff2     = (const float*)d_in[7];
  const float* boff2     = (const float*)d_in[8];
  const float* Wout      = (const float*)d_in[9];
  const float* bout      = (const float*)d_in[10];
  float* out = (float*)d_out;
  char* base = (char*)d_ws;

  const size_t MB = 1u << 20;
  float* coords = (float*)(base);              // 64 KB
  short* qt     = (short*)(base + 1 * MB);     // 4 MB (bh,p,d) pre-scaled
  short* kt     = (short*)(base + 5 * MB);     // 4 MB tiled+swizzled
  short* vt     = (short*)(base + 9 * MB);     // 4 MB tiled+swizzled
  short* bufBh  = (short*)(base + 13 * MB);    // 4 MB q hi -> ao hi
  short* bufBl  = (short*)(base + 17 * MB);    // 4 MB q lo -> ao lo
  short* wb     = (short*)(base + 21 * MB);    // 576 KB conv weights bf16
  short* WH     = (short*)(base + 22 * MB);    // 512 KB Wq/Wk/Wv/Wout hi
  short* WL     = (short*)(base + 23 * MB);    // 512 KB lo
  float* kvT    = (float*)(base + 24 * MB);    // 8 MB kv_map (b,p,c) f32

  dim3 blk(256);
  prep<<<dim3(2432), blk, 0, stream>>>(kv_map, Wq, Wk, Wv, Wout, Woff1,
                                       WH, WL, wb, kvT);
  gemm_mfma<0><<<dim3(256), blk, 0, stream>>>(WH, WL, query_map, nullptr, nullptr,
                                              nullptr, nullptr, qt, bufBh, bufBl);
  conv3x3_off<<<dim3(32, 8), blk, 0, stream>>>(wb, boff1, Woff2, boff2,
                                               bufBh, bufBl, (float2*)coords);
  gemm_kv<<<dim3(256, 2), blk, 0, stream>>>(WH, WL, kvT, (const float2*)coords, kt, vt);
  attn_mfma<<<dim3(16, 64), blk, 0, stream>>>(qt, kt, vt, bufBh, bufBl);
  gemm_mfma<3><<<dim3(256), blk, 0, stream>>>(WH + 196608, WL + 196608, nullptr,
                                              bufBh, bufBl, bout, out,
                                              nullptr, nullptr, nullptr);
}